// Round 1
// baseline (3704.098 us; speedup 1.0000x reference)
//
#include <hip/hip_runtime.h>
#include <math.h>

#define T_DIM 36
#define N_AT 40
#define K_REAL 161
#define KP 164          // padded K = 4*41
#define B_DIM 2
#define F_DIM 20480
#define TF 64           // columns per block
#define NTHREADS 256
#define KPW 41          // k's per wave-thread (KP/4)
#define TPW 9           // t's per wave-thread (36/4)
#define MAXIT 100

// ws layout (floats):
// [0 .. 36*KP)            DA[t][k]  (D, row-major, zero-padded cols 161..163)
// [36*KP .. 36*KP+2)      linv, lam
#define WS_DA 0
#define WS_SCAL (T_DIM * KP)

__global__ void setup_kernel(const float* __restrict__ Drr,
                             const float* __restrict__ Dtheta,
                             float* __restrict__ ws) {
    __shared__ float Dc[KP * T_DIM];   // column-major: Dc[m*36 + i]
    __shared__ float red[NTHREADS];
    int tid = threadIdx.x;
    if (tid < KP) {
        float col[T_DIM];
        if (tid == 0) {
            for (int i = 0; i < T_DIM; ++i) col[i] = 1.0f;
        } else if (tid < K_REAL) {
            int q = (tid - 1) / N_AT, n = (tid - 1) % N_AT;
            float r = Drr[n], th = Dtheta[n];
            float ri = 1.0f;
            for (int i = 0; i < T_DIM; ++i) {
                float c = cosf((float)i * th), s = sinf((float)i * th);
                float sign = (i & 1) ? -1.0f : 1.0f;
                float v;
                if (q == 0)      v = ri * c;
                else if (q == 1) v = sign * ri * c;
                else if (q == 2) v = ri * s;
                else             v = sign * ri * s;
                col[i] = v;
                ri *= r;
            }
        } else {
            for (int i = 0; i < T_DIM; ++i) col[i] = 0.0f;
        }
        float ss = 0.0f;
        for (int i = 0; i < T_DIM; ++i) ss += col[i] * col[i];
        float G = sqrtf(ss);
        float Ginv;
        if (tid >= K_REAL) Ginv = 0.0f;  // pad columns stay zero
        else Ginv = (G == 0.0f) ? (1.0f / sqrtf((float)T_DIM)) : (1.0f / G);
        for (int i = 0; i < T_DIM; ++i) Dc[tid * T_DIM + i] = col[i] * Ginv;
    }
    __syncthreads();
    // Frobenius norm of DtD (real 161x161 block)
    float local = 0.0f;
    for (int p = tid; p < K_REAL * K_REAL; p += NTHREADS) {
        int a = p / K_REAL, b = p % K_REAL;
        float dot = 0.0f;
        for (int i = 0; i < T_DIM; ++i) dot += Dc[a * T_DIM + i] * Dc[b * T_DIM + i];
        local += dot * dot;
    }
    red[tid] = local;
    __syncthreads();
    if (tid == 0) {
        float tot = 0.0f;
        for (int i = 0; i < NTHREADS; ++i) tot += red[i];
        float linv = 1.0f / sqrtf(tot);
        ws[WS_SCAL]     = linv;
        ws[WS_SCAL + 1] = 0.1f * linv;
    }
    // write DA[t][k] = Dc[k][t]
    for (int p = tid; p < KP * T_DIM; p += NTHREADS) {
        int m = p / T_DIM, i = p % T_DIM;
        ws[WS_DA + i * KP + m] = Dc[m * T_DIM + i];
    }
}

__global__ void __launch_bounds__(NTHREADS, 2)
fista_kernel(const float* __restrict__ Y, const float* __restrict__ ws,
             float* __restrict__ out) {
    __shared__ float y_lds[K_REAL * TF];  // [161][64]
    __shared__ float z_lds[T_DIM * TF];   // [36][64]
    const float* DA = ws + WS_DA;
    const float linv = ws[WS_SCAL];
    const float lam  = ws[WS_SCAL + 1];

    const int tid = threadIdx.x;
    const int c   = tid & (TF - 1);
    // wave id: provably uniform -> readfirstlane so D loads become s_load
    const int tg  = __builtin_amdgcn_readfirstlane(tid >> 6);
    const int k0  = KPW * tg;      // this wave owns k in [k0, k0+41)
    const int t0  = TPW * tg;      // this wave owns t in [t0, t0+9)

    const int blk  = blockIdx.x;
    const int b    = blk / (F_DIM / TF);
    const int f    = (blk % (F_DIM / TF)) * TF + c;

    const float* Ycol = Y + (size_t)b * T_DIM * F_DIM + f;

    // ---- DtY + state init ----
    float DtYr[KPW], xo[KPW], yr[KPW];
    #pragma unroll
    for (int i = 0; i < KPW; ++i) DtYr[i] = 0.0f;
    #pragma unroll 4
    for (int t = 0; t < T_DIM; ++t) {
        float yv = Ycol[(size_t)t * F_DIM];
        #pragma unroll
        for (int i = 0; i < KPW; ++i)
            DtYr[i] += DA[t * KP + k0 + i] * yv;
    }
    #pragma unroll
    for (int i = 0; i < KPW; ++i) {
        DtYr[i] *= linv;
        xo[i] = 0.0f;
        yr[i] = 0.0f;
        int k = k0 + i;
        if (k < K_REAL) y_lds[k * TF + c] = 0.0f;
    }
    __syncthreads();

    float tm = 1.0f;
    for (int it = 0; it < MAXIT; ++it) {
        // ---- phase A: z = D * y  (rows t0..t0+8 of z for this wave) ----
        float za[TPW];
        #pragma unroll
        for (int i = 0; i < TPW; ++i) za[i] = 0.0f;
        #pragma unroll 7
        for (int j = 0; j < K_REAL; ++j) {
            float yv = y_lds[j * TF + c];
            #pragma unroll
            for (int i = 0; i < TPW; ++i)
                za[i] += DA[(t0 + i) * KP + j] * yv;
        }
        #pragma unroll
        for (int i = 0; i < TPW; ++i) z_lds[(t0 + i) * TF + c] = za[i];
        __syncthreads();

        float tn = 0.5f * (1.0f + sqrtf(1.0f + 4.0f * tm * tm));
        float tt = (tm - 1.0f) / tn;
        tm = tn;

        // ---- phase B: w = D^T * z, then shrink + momentum ----
        float w[KPW];
        #pragma unroll
        for (int i = 0; i < KPW; ++i) w[i] = 0.0f;
        #pragma unroll 4
        for (int t = 0; t < T_DIM; ++t) {
            float zv = z_lds[t * TF + c];
            #pragma unroll
            for (int i = 0; i < KPW; ++i)
                w[i] += DA[t * KP + k0 + i] * zv;
        }
        #pragma unroll
        for (int i = 0; i < KPW; ++i) {
            float v  = yr[i] - linv * w[i] + DtYr[i];
            float av = fabsf(v) - lam;
            float xn = (av > 0.0f) ? copysignf(av, v) : 0.0f;
            yr[i] = (1.0f + tt) * xn - tt * xo[i];
            xo[i] = xn;
            int k = k0 + i;
            if (k < K_REAL) y_lds[k * TF + c] = yr[i];
        }
        __syncthreads();
    }

    // ---- output ----
    float* Ocol = out + (size_t)b * K_REAL * F_DIM + f;
    #pragma unroll
    for (int i = 0; i < KPW; ++i) {
        int k = k0 + i;
        if (k < K_REAL) Ocol[(size_t)k * F_DIM] = xo[i];
    }
}

extern "C" void kernel_launch(void* const* d_in, const int* in_sizes, int n_in,
                              void* d_out, int out_size, void* d_ws, size_t ws_size,
                              hipStream_t stream) {
    const float* x      = (const float*)d_in[0];
    const float* Drr    = (const float*)d_in[1];
    const float* Dtheta = (const float*)d_in[2];
    float* out = (float*)d_out;
    float* ws  = (float*)d_ws;

    hipLaunchKernelGGL(setup_kernel, dim3(1), dim3(NTHREADS), 0, stream,
                       Drr, Dtheta, ws);
    hipLaunchKernelGGL(fista_kernel, dim3((B_DIM * F_DIM) / TF), dim3(NTHREADS),
                       0, stream, x, ws, out);
}

// Round 2
// 2663.472 us; speedup vs baseline: 1.3907x; 1.3907x over previous
//
#include <hip/hip_runtime.h>
#include <math.h>

#define T_DIM 36
#define T_PAD 40
#define N_AT 40
#define K_REAL 161
#define KP 168          // padded K = 8*21
#define B_DIM 2
#define F_DIM 20480
#define TF 64           // columns per block (one wave width)
#define NTHREADS 512    // 8 waves
#define NW 8
#define KPW 21          // k's per thread (KP/NW)
#define TPW 5           // t's per thread (T_PAD/NW)
#define MAXIT 100

// ws layout (floats):
// [WS_DA .. +36*KP)     DA[t][k]   row-major, zero-padded cols 161..167
// [WS_DT .. +KP*T_PAD)  DT[k][t]   row-major (transposed D), t 36..39 zero
// [WS_SCAL .. +2)       linv, lam
#define WS_DA 0
#define WS_DT (T_DIM * KP)
#define WS_SCAL (WS_DA + T_DIM * KP + KP * T_PAD)

__global__ void setup_kernel(const float* __restrict__ Drr,
                             const float* __restrict__ Dtheta,
                             float* __restrict__ ws) {
    __shared__ float Dc[KP * T_DIM];   // column-major: Dc[m*36 + i]
    __shared__ float red[256];
    int tid = threadIdx.x;
    if (tid < KP) {
        float col[T_DIM];
        if (tid == 0) {
            for (int i = 0; i < T_DIM; ++i) col[i] = 1.0f;
        } else if (tid < K_REAL) {
            int q = (tid - 1) / N_AT, n = (tid - 1) % N_AT;
            float r = Drr[n], th = Dtheta[n];
            float ri = 1.0f;
            for (int i = 0; i < T_DIM; ++i) {
                float c = cosf((float)i * th), s = sinf((float)i * th);
                float sign = (i & 1) ? -1.0f : 1.0f;
                float v;
                if (q == 0)      v = ri * c;
                else if (q == 1) v = sign * ri * c;
                else if (q == 2) v = ri * s;
                else             v = sign * ri * s;
                col[i] = v;
                ri *= r;
            }
        } else {
            for (int i = 0; i < T_DIM; ++i) col[i] = 0.0f;
        }
        float ss = 0.0f;
        for (int i = 0; i < T_DIM; ++i) ss += col[i] * col[i];
        float G = sqrtf(ss);
        float Ginv;
        if (tid >= K_REAL) Ginv = 0.0f;  // pad columns stay zero
        else Ginv = (G == 0.0f) ? (1.0f / sqrtf((float)T_DIM)) : (1.0f / G);
        for (int i = 0; i < T_DIM; ++i) Dc[tid * T_DIM + i] = col[i] * Ginv;
    }
    __syncthreads();
    // Frobenius norm of DtD (real 161x161 block)
    float local = 0.0f;
    for (int p = tid; p < K_REAL * K_REAL; p += 256) {
        int a = p / K_REAL, b = p % K_REAL;
        float dot = 0.0f;
        for (int i = 0; i < T_DIM; ++i) dot += Dc[a * T_DIM + i] * Dc[b * T_DIM + i];
        local += dot * dot;
    }
    red[tid] = local;
    __syncthreads();
    if (tid == 0) {
        float tot = 0.0f;
        for (int i = 0; i < 256; ++i) tot += red[i];
        float linv = 1.0f / sqrtf(tot);
        ws[WS_SCAL]     = linv;
        ws[WS_SCAL + 1] = 0.1f * linv;
    }
    // DA[t][k] = Dc[k][t]
    for (int p = tid; p < KP * T_DIM; p += 256) {
        int m = p / T_DIM, i = p % T_DIM;
        ws[WS_DA + i * KP + m] = Dc[m * T_DIM + i];
    }
    // DT[k][t] = Dc[k][t], t padded to 40 with zeros
    for (int p = tid; p < KP * T_PAD; p += 256) {
        int m = p / T_PAD, i = p % T_PAD;
        ws[WS_DT + m * T_PAD + i] = (i < T_DIM) ? Dc[m * T_DIM + i] : 0.0f;
    }
}

__global__ void __launch_bounds__(NTHREADS, 6)
fista_kernel(const float* __restrict__ Y, const float* __restrict__ ws,
             float* __restrict__ out) {
    __shared__ float y_lds[K_REAL * TF];  // [161][64]
    __shared__ float z_lds[T_PAD * TF];   // [40][64]
    const float* DA = ws + WS_DA;
    const float* DT = ws + WS_DT;
    const float linv = ws[WS_SCAL];
    const float lam  = ws[WS_SCAL + 1];

    const int tid = threadIdx.x;
    const int c   = tid & (TF - 1);
    // wave id: uniform -> readfirstlane so D loads become s_load
    const int tg  = __builtin_amdgcn_readfirstlane(tid >> 6);
    const int k0  = KPW * tg;      // this wave owns k in [k0, k0+21)
    const int t0  = TPW * tg;      // this wave owns t in [t0, t0+5)

    const int blk  = blockIdx.x;
    const int b    = blk / (F_DIM / TF);
    const int f    = (blk % (F_DIM / TF)) * TF + c;

    const float* Ycol = Y + (size_t)b * T_DIM * F_DIM + f;

    // ---- DtY + state init ----
    float DtYr[KPW], xo[KPW];
    #pragma unroll
    for (int i = 0; i < KPW; ++i) DtYr[i] = 0.0f;
    #pragma unroll 4
    for (int t = 0; t < T_DIM; ++t) {
        float yv = Ycol[(size_t)t * F_DIM];
        #pragma unroll
        for (int i = 0; i < KPW; ++i)
            DtYr[i] += DA[t * KP + k0 + i] * yv;
    }
    #pragma unroll
    for (int i = 0; i < KPW; ++i) {
        DtYr[i] *= linv;
        xo[i] = 0.0f;
        int k = k0 + i;
        if (k < K_REAL) y_lds[k * TF + c] = 0.0f;
    }
    __syncthreads();

    float tm = 1.0f;
    for (int it = 0; it < MAXIT; ++it) {
        // ---- phase A: z = D * y  (rows t0..t0+4 for this wave) ----
        // DT[j][t0..t0+5) is contiguous -> batched s_load
        float za[TPW];
        #pragma unroll
        for (int i = 0; i < TPW; ++i) za[i] = 0.0f;
        const float* DTw = DT + t0;
        #pragma unroll 7
        for (int j = 0; j < K_REAL; ++j) {
            float yv = y_lds[j * TF + c];
            #pragma unroll
            for (int i = 0; i < TPW; ++i)
                za[i] += DTw[j * T_PAD + i] * yv;
        }
        #pragma unroll
        for (int i = 0; i < TPW; ++i) z_lds[(t0 + i) * TF + c] = za[i];
        __syncthreads();

        float tn = 0.5f * (1.0f + sqrtf(1.0f + 4.0f * tm * tm));
        float tt = (tm - 1.0f) / tn;
        tm = tn;

        // ---- phase B: w = D^T * z, then shrink + momentum ----
        float w[KPW];
        #pragma unroll
        for (int i = 0; i < KPW; ++i) w[i] = 0.0f;
        #pragma unroll 4
        for (int t = 0; t < T_DIM; ++t) {
            float zv = z_lds[t * TF + c];
            #pragma unroll
            for (int i = 0; i < KPW; ++i)
                w[i] += DA[t * KP + k0 + i] * zv;
        }
        #pragma unroll
        for (int i = 0; i < KPW; ++i) {
            int k = k0 + i;
            float yv = (k < K_REAL) ? y_lds[k * TF + c] : 0.0f;
            float v  = yv - linv * w[i] + DtYr[i];
            float av = fabsf(v) - lam;
            float xn = (av > 0.0f) ? copysignf(av, v) : 0.0f;
            float yn = (1.0f + tt) * xn - tt * xo[i];
            xo[i] = xn;
            if (k < K_REAL) y_lds[k * TF + c] = yn;
        }
        __syncthreads();
    }

    // ---- output ----
    float* Ocol = out + (size_t)b * K_REAL * F_DIM + f;
    #pragma unroll
    for (int i = 0; i < KPW; ++i) {
        int k = k0 + i;
        if (k < K_REAL) Ocol[(size_t)k * F_DIM] = xo[i];
    }
}

extern "C" void kernel_launch(void* const* d_in, const int* in_sizes, int n_in,
                              void* d_out, int out_size, void* d_ws, size_t ws_size,
                              hipStream_t stream) {
    const float* x      = (const float*)d_in[0];
    const float* Drr    = (const float*)d_in[1];
    const float* Dtheta = (const float*)d_in[2];
    float* out = (float*)d_out;
    float* ws  = (float*)d_ws;

    hipLaunchKernelGGL(setup_kernel, dim3(1), dim3(256), 0, stream,
                       Drr, Dtheta, ws);
    hipLaunchKernelGGL(fista_kernel, dim3((B_DIM * F_DIM) / TF), dim3(NTHREADS),
                       0, stream, x, ws, out);
}

// Round 3
// 780.960 us; speedup vs baseline: 4.7430x; 3.4105x over previous
//
#include <hip/hip_runtime.h>
#include <math.h>

typedef _Float16 half8 __attribute__((ext_vector_type(8)));
typedef _Float16 half4 __attribute__((ext_vector_type(4)));
typedef float    f32x4 __attribute__((ext_vector_type(4)));

#define T_DIM 36
#define N_AT 40
#define K_REAL 161
#define MT 12           // 12 M-tiles of 16 = 192 rows (161 real)
#define KS 6            // 6 K-steps of 32 = 192 (161 real)
#define KS2 2           // DtY K-steps over t (36 -> 64)
#define B_DIM 2
#define F_DIM 20480
#define CB 32           // columns per block
#define MG 4            // m-groups (waves along M)
#define MLOC 3          // M-tiles per wave
#define NTHREADS 512    // 8 waves = 4 mg x 2 ng
#define MAXIT 100
#define YK 200          // padded k-stride in y LDS (f16 units; 400B = 100 dwords -> banks spread)
#define YST 72          // Ystage t-stride (f16 units; 144B = 36 dwords -> banks spread)

// ws layout (bytes):
//  [0..64): scalars  (float linv @0, float lam @4)
//  [64 .. 64+144*1024): A-hat fragments, frag idx = (Mt*6+ks)*2+term, 64 lanes x 8 f16
//  [.. +48*1024): Dthat fragments,      frag idx = (Mt*2+ks2)*2+term
#define WS_AFRAG_OFF 64
#define AFRAG_BYTES (144 * 1024)
#define WS_DFRAG_OFF (WS_AFRAG_OFF + AFRAG_BYTES)

#define MFMA16(a, b, c) __builtin_amdgcn_mfma_f32_16x16x32_f16((a), (b), (c), 0, 0, 0)

__global__ void setup_kernel(const float* __restrict__ Drr,
                             const float* __restrict__ Dtheta,
                             float* __restrict__ ws) {
    __shared__ float Dl[K_REAL][T_DIM];   // normalized dictionary, [col k][t]
    __shared__ float red[NTHREADS];
    __shared__ float s_linv;
    int tid = threadIdx.x;

    // ---- build normalized dictionary columns ----
    if (tid < K_REAL) {
        float col[T_DIM];
        if (tid == 0) {
            for (int i = 0; i < T_DIM; ++i) col[i] = 1.0f;
        } else {
            int q = (tid - 1) / N_AT, n = (tid - 1) % N_AT;
            float r = Drr[n], th = Dtheta[n];
            float ri = 1.0f;
            for (int i = 0; i < T_DIM; ++i) {
                float c = cosf((float)i * th), s = sinf((float)i * th);
                float sign = (i & 1) ? -1.0f : 1.0f;
                float v;
                if (q == 0)      v = ri * c;
                else if (q == 1) v = sign * ri * c;
                else if (q == 2) v = ri * s;
                else             v = sign * ri * s;
                col[i] = v;
                ri *= r;
            }
        }
        float ss = 0.0f;
        for (int i = 0; i < T_DIM; ++i) ss += col[i] * col[i];
        float G = sqrtf(ss);
        float Ginv = (G == 0.0f) ? (1.0f / sqrtf((float)T_DIM)) : (1.0f / G);
        for (int i = 0; i < T_DIM; ++i) Dl[tid][i] = col[i] * Ginv;
    }
    __syncthreads();

    // ---- linv = 1 / frobenius(DtD) ----
    float local = 0.0f;
    for (int p = tid; p < K_REAL * K_REAL; p += NTHREADS) {
        int a = p / K_REAL, b = p % K_REAL;
        float dot = 0.0f;
        for (int i = 0; i < T_DIM; ++i) dot += Dl[a][i] * Dl[b][i];
        local += dot * dot;
    }
    red[tid] = local;
    __syncthreads();
    if (tid == 0) {
        float tot = 0.0f;
        for (int i = 0; i < NTHREADS; ++i) tot += red[i];
        float linv = 1.0f / sqrtf(tot);
        s_linv = linv;
        ws[0] = linv;
        ws[1] = 0.1f * linv;
    }
    __syncthreads();
    float linv = s_linv;

    // ---- A-hat fragments: A = I - linv * DtD, f16 hi/lo, A-operand layout ----
    // frag elem: lane = tid>>3, e = tid&7 ; m = Mt*16+(lane&15) ; k = ks*32+(lane>>4)*8+e
    _Float16* wsA = (_Float16*)((char*)ws + WS_AFRAG_OFF);
    int lane = tid >> 3, e = tid & 7;
    int fm = lane & 15, fq = lane >> 4;
    for (int p = 0; p < MT * KS; ++p) {
        int Mt = p / KS, ks = p % KS;
        int m = Mt * 16 + fm;
        int k = ks * 32 + fq * 8 + e;
        float v = 0.0f;
        if (m < K_REAL && k < K_REAL) {
            float dot = 0.0f;
            for (int t = 0; t < T_DIM; ++t) dot += Dl[m][t] * Dl[k][t];
            v = ((m == k) ? 1.0f : 0.0f) - linv * dot;
        }
        _Float16 h = (_Float16)v;
        _Float16 l = (_Float16)(v - (float)h);
        int base = (p * 2) * 512 + lane * 8 + e;
        wsA[base]       = h;
        wsA[base + 512] = l;
    }

    // ---- Dthat fragments: Dthat[k][t] = linv * D[t][k], A-operand layout over t ----
    _Float16* wsD = (_Float16*)((char*)ws + WS_DFRAG_OFF);
    for (int p = 0; p < MT * KS2; ++p) {
        int Mt = p / KS2, ks2 = p % KS2;
        int kr = Mt * 16 + fm;
        int t  = ks2 * 32 + fq * 8 + e;
        float v = (kr < K_REAL && t < T_DIM) ? linv * Dl[kr][t] : 0.0f;
        _Float16 h = (_Float16)v;
        _Float16 l = (_Float16)(v - (float)h);
        int base = (p * 2) * 512 + lane * 8 + e;
        wsD[base]       = h;
        wsD[base + 512] = l;
    }
}

__global__ void __launch_bounds__(NTHREADS, 2)
fista_mfma(const float* __restrict__ Y, const float* __restrict__ ws,
           float* __restrict__ out) {
    // ping-pong y in f16 hi/lo, [buf][part][col][k]
    __shared__ __align__(16) _Float16 ybuf[2][2][CB][YK];

    const float lam = ((const float*)ws)[1];
    const half8* Afp = (const half8*)((const char*)ws + WS_AFRAG_OFF); // 64 half8 per frag
    const half8* Dfp = (const half8*)((const char*)ws + WS_DFRAG_OFF);

    const int tid  = threadIdx.x;
    const int lane = tid & 63;
    const int wv   = __builtin_amdgcn_readfirstlane(tid >> 6); // 0..7
    const int mg   = wv >> 1;          // 0..3  (M-group)
    const int ng   = wv & 1;           // 0..1  (N-group)
    const int quad = lane >> 4;
    const int cl   = ng * 16 + (lane & 15);   // local column 0..31

    const int blk = blockIdx.x;
    const int b   = blk / (F_DIM / CB);
    const int f0  = (blk % (F_DIM / CB)) * CB;

    // ---- stage Y (f16 hi/lo, B-operand friendly [part][c][t]) into ybuf[1] area ----
    _Float16* Yst = &ybuf[1][0][0][0];     // uses 2*CB*YST*2 = 9216 B of the 25.6 KB
    const float* Yb = Y + (size_t)b * T_DIM * F_DIM + f0;
    for (int idx = tid; idx < 64 * CB; idx += NTHREADS) {
        int t = idx / CB, c = idx % CB;
        float v = (t < T_DIM) ? Yb[(size_t)t * F_DIM + c] : 0.0f;
        _Float16 h = (_Float16)v;
        _Float16 l = (_Float16)(v - (float)h);
        Yst[c * YST + t]            = h;
        Yst[CB * YST + c * YST + t] = l;
    }
    // ---- zero ybuf[0] (y = 0 initial iterate, incl. pad rows) ----
    int4* zb = (int4*)&ybuf[0][0][0][0];
    for (int idx = tid; idx < (2 * CB * YK * 2) / 16; idx += NTHREADS)
        zb[idx] = int4{0, 0, 0, 0};
    __syncthreads();

    // ---- DtY via MFMA (3-term split), lands directly in C-layout regs ----
    f32x4 dty[MLOC];
    #pragma unroll
    for (int ml = 0; ml < MLOC; ++ml) dty[ml] = f32x4{0.f, 0.f, 0.f, 0.f};
    #pragma unroll
    for (int ks2 = 0; ks2 < KS2; ++ks2) {
        const _Float16* yp = Yst + cl * YST + ks2 * 32 + quad * 8;
        half8 yh = *(const half8*)yp;
        half8 yl = *(const half8*)(yp + CB * YST);
        #pragma unroll
        for (int ml = 0; ml < MLOC; ++ml) {
            int Mt = mg * MLOC + ml;
            half8 dh = Dfp[((Mt * KS2 + ks2) * 2 + 0) * 64 + lane];
            half8 dl = Dfp[((Mt * KS2 + ks2) * 2 + 1) * 64 + lane];
            dty[ml] = MFMA16(dh, yh, dty[ml]);
            dty[ml] = MFMA16(dh, yl, dty[ml]);
            dty[ml] = MFMA16(dl, yh, dty[ml]);
        }
    }
    __syncthreads();   // all waves done reading Yst before iter-0 writes ybuf[1]

    // ---- load persistent A-hat fragments (144 VGPRs, live across all iters) ----
    half8 Af[MLOC][KS][2];
    #pragma unroll
    for (int ml = 0; ml < MLOC; ++ml)
        #pragma unroll
        for (int ks = 0; ks < KS; ++ks)
            #pragma unroll
            for (int term = 0; term < 2; ++term)
                Af[ml][ks][term] =
                    Afp[(((mg * MLOC + ml) * KS + ks) * 2 + term) * 64 + lane];

    float xold[MLOC][4];
    #pragma unroll
    for (int ml = 0; ml < MLOC; ++ml)
        #pragma unroll
        for (int r = 0; r < 4; ++r) xold[ml][r] = 0.0f;

    float tm = 1.0f;
    int p = 0;
    for (int it = 0; it < MAXIT; ++it) {
        f32x4 acc[MLOC];
        #pragma unroll
        for (int ml = 0; ml < MLOC; ++ml) acc[ml] = dty[ml];

        #pragma unroll
        for (int ks = 0; ks < KS; ++ks) {
            const _Float16* yp = &ybuf[p][0][cl][ks * 32 + quad * 8];
            half8 yh = *(const half8*)yp;
            half8 yl = *(const half8*)(yp + CB * YK);
            #pragma unroll
            for (int ml = 0; ml < MLOC; ++ml) {
                acc[ml] = MFMA16(Af[ml][ks][0], yh, acc[ml]);
                acc[ml] = MFMA16(Af[ml][ks][0], yl, acc[ml]);
                acc[ml] = MFMA16(Af[ml][ks][1], yh, acc[ml]);
            }
        }

        float tn = 0.5f * (1.0f + sqrtf(1.0f + 4.0f * tm * tm));
        float tt = (tm - 1.0f) / tn;
        tm = tn;

        #pragma unroll
        for (int ml = 0; ml < MLOC; ++ml) {
            half4 hv, lv;
            #pragma unroll
            for (int r = 0; r < 4; ++r) {
                float v  = acc[ml][r];              // = A*y + DtY (acc seeded w/ DtY)
                float s  = fabsf(v) - lam;
                float xn = (s > 0.0f) ? copysignf(s, v) : 0.0f;
                float yn = (1.0f + tt) * xn - tt * xold[ml][r];
                xold[ml][r] = xn;
                _Float16 h = (_Float16)yn;
                hv[r] = h;
                lv[r] = (_Float16)(yn - (float)h);
            }
            int k0 = (mg * MLOC + ml) * 16 + quad * 4;
            *(half4*)&ybuf[1 - p][0][cl][k0] = hv;
            *(half4*)&ybuf[1 - p][1][cl][k0] = lv;
        }
        __syncthreads();
        p ^= 1;
    }

    // ---- output x (fp32) ----
    float* ob = out + (size_t)b * K_REAL * F_DIM + f0 + cl;
    #pragma unroll
    for (int ml = 0; ml < MLOC; ++ml)
        #pragma unroll
        for (int r = 0; r < 4; ++r) {
            int k = (mg * MLOC + ml) * 16 + quad * 4 + r;
            if (k < K_REAL) ob[(size_t)k * F_DIM] = xold[ml][r];
        }
}

extern "C" void kernel_launch(void* const* d_in, const int* in_sizes, int n_in,
                              void* d_out, int out_size, void* d_ws, size_t ws_size,
                              hipStream_t stream) {
    const float* x      = (const float*)d_in[0];
    const float* Drr    = (const float*)d_in[1];
    const float* Dtheta = (const float*)d_in[2];
    float* out = (float*)d_out;
    float* ws  = (float*)d_ws;

    hipLaunchKernelGGL(setup_kernel, dim3(1), dim3(NTHREADS), 0, stream,
                       Drr, Dtheta, ws);
    hipLaunchKernelGGL(fista_mfma, dim3((B_DIM * F_DIM) / CB), dim3(NTHREADS),
                       0, stream, x, ws, out);
}

// Round 5
// 689.063 us; speedup vs baseline: 5.3756x; 1.1334x over previous
//
#include <hip/hip_runtime.h>
#include <math.h>

typedef _Float16 half8 __attribute__((ext_vector_type(8)));
typedef _Float16 half4 __attribute__((ext_vector_type(4)));
typedef float    f32x4 __attribute__((ext_vector_type(4)));

#define T_DIM 36
#define N_AT 40
#define K_REAL 161
#define MT 12           // 12 M-tiles of 16 = 192 rows (161 real)
#define KS 6            // 6 K-steps of 32 = 192 (161 real)
#define KS2 2           // DtY K-steps over t (36 -> 64)
#define B_DIM 2
#define F_DIM 20480
#define CB 16           // columns per block (one 16-wide MFMA N-tile)
#define MLOC 3          // M-tiles per wave
#define NTHREADS 256    // 4 waves -> 25.6 KB LDS -> 2 independent blocks/CU
#define SETUP_T 512     // MUST be 512: frag builder needs tid>>3 to span 64 lanes
#define MAXIT 100
#define YK 200          // padded k-stride in y LDS (f16; 100 dwords -> bank stride 4)
#define YST 72          // Ystage t-stride (f16 units)

// ws layout (bytes):
//  [0..64): scalars  (float linv @0, float lam @4)
//  [64 .. 64+144*1024): A-hat fragments, frag idx = (Mt*6+ks)*2+term, 64 lanes x 8 f16
//  [.. +48*1024): Dthat fragments,      frag idx = (Mt*2+ks2)*2+term
#define WS_AFRAG_OFF 64
#define AFRAG_BYTES (144 * 1024)
#define WS_DFRAG_OFF (WS_AFRAG_OFF + AFRAG_BYTES)

#define MFMA16(a, b, c) __builtin_amdgcn_mfma_f32_16x16x32_f16((a), (b), (c), 0, 0, 0)

__global__ void setup_kernel(const float* __restrict__ Drr,
                             const float* __restrict__ Dtheta,
                             float* __restrict__ ws) {
    __shared__ float Dl[K_REAL][T_DIM];   // normalized dictionary, [col k][t]
    __shared__ float red[SETUP_T];
    __shared__ float s_linv;
    int tid = threadIdx.x;

    // ---- build normalized dictionary columns ----
    if (tid < K_REAL) {
        float col[T_DIM];
        if (tid == 0) {
            for (int i = 0; i < T_DIM; ++i) col[i] = 1.0f;
        } else {
            int q = (tid - 1) / N_AT, n = (tid - 1) % N_AT;
            float r = Drr[n], th = Dtheta[n];
            float ri = 1.0f;
            for (int i = 0; i < T_DIM; ++i) {
                float c = cosf((float)i * th), s = sinf((float)i * th);
                float sign = (i & 1) ? -1.0f : 1.0f;
                float v;
                if (q == 0)      v = ri * c;
                else if (q == 1) v = sign * ri * c;
                else if (q == 2) v = ri * s;
                else             v = sign * ri * s;
                col[i] = v;
                ri *= r;
            }
        }
        float ss = 0.0f;
        for (int i = 0; i < T_DIM; ++i) ss += col[i] * col[i];
        float G = sqrtf(ss);
        float Ginv = (G == 0.0f) ? (1.0f / sqrtf((float)T_DIM)) : (1.0f / G);
        for (int i = 0; i < T_DIM; ++i) Dl[tid][i] = col[i] * Ginv;
    }
    __syncthreads();

    // ---- linv = 1 / frobenius(DtD) ----
    float local = 0.0f;
    for (int p = tid; p < K_REAL * K_REAL; p += SETUP_T) {
        int a = p / K_REAL, b = p % K_REAL;
        float dot = 0.0f;
        for (int i = 0; i < T_DIM; ++i) dot += Dl[a][i] * Dl[b][i];
        local += dot * dot;
    }
    red[tid] = local;
    __syncthreads();
    if (tid == 0) {
        float tot = 0.0f;
        for (int i = 0; i < SETUP_T; ++i) tot += red[i];
        float linv = 1.0f / sqrtf(tot);
        s_linv = linv;
        ws[0] = linv;
        ws[1] = 0.1f * linv;
    }
    __syncthreads();
    float linv = s_linv;

    // ---- A-hat fragments: A = I - linv * DtD, f16 hi/lo, A-operand layout ----
    // frag elem: lane = tid>>3 (0..63 with 512 thr), e = tid&7
    //   m = Mt*16+(lane&15) ; k = ks*32+(lane>>4)*8+e
    _Float16* wsA = (_Float16*)((char*)ws + WS_AFRAG_OFF);
    int lane = tid >> 3, e = tid & 7;
    int fm = lane & 15, fq = lane >> 4;
    for (int p = 0; p < MT * KS; ++p) {
        int Mt = p / KS, ks = p % KS;
        int m = Mt * 16 + fm;
        int k = ks * 32 + fq * 8 + e;
        float v = 0.0f;
        if (m < K_REAL && k < K_REAL) {
            float dot = 0.0f;
            for (int t = 0; t < T_DIM; ++t) dot += Dl[m][t] * Dl[k][t];
            v = ((m == k) ? 1.0f : 0.0f) - linv * dot;
        }
        _Float16 h = (_Float16)v;
        _Float16 l = (_Float16)(v - (float)h);
        int base = (p * 2) * 512 + lane * 8 + e;
        wsA[base]       = h;
        wsA[base + 512] = l;
    }

    // ---- Dthat fragments: Dthat[k][t] = linv * D[t][k], A-operand layout over t ----
    _Float16* wsD = (_Float16*)((char*)ws + WS_DFRAG_OFF);
    for (int p = 0; p < MT * KS2; ++p) {
        int Mt = p / KS2, ks2 = p % KS2;
        int kr = Mt * 16 + fm;
        int t  = ks2 * 32 + fq * 8 + e;
        float v = (kr < K_REAL && t < T_DIM) ? linv * Dl[kr][t] : 0.0f;
        _Float16 h = (_Float16)v;
        _Float16 l = (_Float16)(v - (float)h);
        int base = (p * 2) * 512 + lane * 8 + e;
        wsD[base]       = h;
        wsD[base + 512] = l;
    }
}

__global__ void __launch_bounds__(NTHREADS, 2)
fista_mfma(const float* __restrict__ Y, const float* __restrict__ ws,
           float* __restrict__ out) {
    // ping-pong y in f16 hi/lo, [buf][part][col][k]  (25.6 KB -> 2 blocks/CU)
    __shared__ __align__(16) _Float16 ybuf[2][2][CB][YK];

    const float lam = ((const float*)ws)[1];
    const half8* Afp = (const half8*)((const char*)ws + WS_AFRAG_OFF); // 64 half8 per frag
    const half8* Dfp = (const half8*)((const char*)ws + WS_DFRAG_OFF);

    const int tid  = threadIdx.x;
    const int lane = tid & 63;
    const int mg   = __builtin_amdgcn_readfirstlane(tid >> 6); // 0..3 (M-group)
    const int quad = lane >> 4;
    const int cl   = lane & 15;        // local column 0..15

    const int blk = blockIdx.x;
    const int b   = blk / (F_DIM / CB);
    const int f0  = (blk % (F_DIM / CB)) * CB;

    // ---- stage Y (f16 hi/lo, B-operand friendly [part][c][t]) into ybuf[1] area ----
    _Float16* Yst = &ybuf[1][0][0][0];     // 2*CB*YST*2 = 4608 B of the 12.8 KB buffer
    const float* Yb = Y + (size_t)b * T_DIM * F_DIM + f0;
    for (int idx = tid; idx < 64 * CB; idx += NTHREADS) {
        int t = idx / CB, c = idx % CB;
        float v = (t < T_DIM) ? Yb[(size_t)t * F_DIM + c] : 0.0f;
        _Float16 h = (_Float16)v;
        _Float16 l = (_Float16)(v - (float)h);
        Yst[c * YST + t]            = h;
        Yst[CB * YST + c * YST + t] = l;
    }
    // ---- zero ybuf[0] (y = 0 initial iterate, incl. pad rows) ----
    int4* zb = (int4*)&ybuf[0][0][0][0];
    for (int idx = tid; idx < (2 * CB * YK * 2) / 16; idx += NTHREADS)
        zb[idx] = int4{0, 0, 0, 0};
    __syncthreads();

    // ---- DtY via MFMA (3-term split), lands directly in C-layout regs ----
    f32x4 dty[MLOC];
    #pragma unroll
    for (int ml = 0; ml < MLOC; ++ml) dty[ml] = f32x4{0.f, 0.f, 0.f, 0.f};
    #pragma unroll
    for (int ks2 = 0; ks2 < KS2; ++ks2) {
        const _Float16* yp = Yst + cl * YST + ks2 * 32 + quad * 8;
        half8 yh = *(const half8*)yp;
        half8 yl = *(const half8*)(yp + CB * YST);
        #pragma unroll
        for (int ml = 0; ml < MLOC; ++ml) {
            int Mt = mg * MLOC + ml;
            half8 dh = Dfp[((Mt * KS2 + ks2) * 2 + 0) * 64 + lane];
            half8 dl = Dfp[((Mt * KS2 + ks2) * 2 + 1) * 64 + lane];
            dty[ml] = MFMA16(dh, yh, dty[ml]);
            dty[ml] = MFMA16(dh, yl, dty[ml]);
            dty[ml] = MFMA16(dl, yh, dty[ml]);
        }
    }
    __syncthreads();   // all waves done reading Yst before iter-0 writes ybuf[1]

    // ---- load persistent A-hat fragments (144 regs, live across all iters) ----
    half8 Af[MLOC][KS][2];
    #pragma unroll
    for (int ml = 0; ml < MLOC; ++ml)
        #pragma unroll
        for (int ks = 0; ks < KS; ++ks)
            #pragma unroll
            for (int term = 0; term < 2; ++term)
                Af[ml][ks][term] =
                    Afp[(((mg * MLOC + ml) * KS + ks) * 2 + term) * 64 + lane];

    float xold[MLOC][4];
    #pragma unroll
    for (int ml = 0; ml < MLOC; ++ml)
        #pragma unroll
        for (int r = 0; r < 4; ++r) xold[ml][r] = 0.0f;

    float tm = 1.0f;
    int p = 0;
    for (int it = 0; it < MAXIT; ++it) {
        f32x4 acc[MLOC];
        #pragma unroll
        for (int ml = 0; ml < MLOC; ++ml) acc[ml] = dty[ml];

        #pragma unroll
        for (int ks = 0; ks < KS; ++ks) {
            const _Float16* yp = &ybuf[p][0][cl][ks * 32 + quad * 8];
            half8 yh = *(const half8*)yp;
            half8 yl = *(const half8*)(yp + CB * YK);
            #pragma unroll
            for (int ml = 0; ml < MLOC; ++ml) {
                acc[ml] = MFMA16(Af[ml][ks][0], yh, acc[ml]);
                acc[ml] = MFMA16(Af[ml][ks][0], yl, acc[ml]);
                acc[ml] = MFMA16(Af[ml][ks][1], yh, acc[ml]);
            }
        }

        float tn = 0.5f * (1.0f + sqrtf(1.0f + 4.0f * tm * tm));
        float tt = (tm - 1.0f) / tn;
        tm = tn;

        #pragma unroll
        for (int ml = 0; ml < MLOC; ++ml) {
            half4 hv, lv;
            #pragma unroll
            for (int r = 0; r < 4; ++r) {
                float v  = acc[ml][r];              // = A*y + DtY (acc seeded w/ DtY)
                float s  = fmaxf(fabsf(v) - lam, 0.0f);
                float xn = copysignf(s, v);
                float yn = (1.0f + tt) * xn - tt * xold[ml][r];
                xold[ml][r] = xn;
                _Float16 h = (_Float16)yn;
                hv[r] = h;
                lv[r] = (_Float16)(yn - (float)h);
            }
            int k0 = (mg * MLOC + ml) * 16 + quad * 4;
            *(half4*)&ybuf[1 - p][0][cl][k0] = hv;
            *(half4*)&ybuf[1 - p][1][cl][k0] = lv;
        }
        __syncthreads();
        p ^= 1;
    }

    // ---- output x (fp32) ----
    float* ob = out + (size_t)b * K_REAL * F_DIM + f0 + cl;
    #pragma unroll
    for (int ml = 0; ml < MLOC; ++ml)
        #pragma unroll
        for (int r = 0; r < 4; ++r) {
            int k = (mg * MLOC + ml) * 16 + quad * 4 + r;
            if (k < K_REAL) ob[(size_t)k * F_DIM] = xold[ml][r];
        }
}

extern "C" void kernel_launch(void* const* d_in, const int* in_sizes, int n_in,
                              void* d_out, int out_size, void* d_ws, size_t ws_size,
                              hipStream_t stream) {
    const float* x      = (const float*)d_in[0];
    const float* Drr    = (const float*)d_in[1];
    const float* Dtheta = (const float*)d_in[2];
    float* out = (float*)d_out;
    float* ws  = (float*)d_ws;

    hipLaunchKernelGGL(setup_kernel, dim3(1), dim3(SETUP_T), 0, stream,
                       Drr, Dtheta, ws);
    hipLaunchKernelGGL(fista_mfma, dim3((B_DIM * F_DIM) / CB), dim3(NTHREADS),
                       0, stream, x, ws, out);
}